// Round 8
// baseline (482.083 us; speedup 1.0000x reference)
//
#include <hip/hip_runtime.h>

// Correlation: out[b,(p+4)*9+(q+4),y,x] = (1/128) * sum_c A[b,c,y,x]*B[b,c,y+p,x+q]
// A,B = (8,128,128,128) fp32; out = (8,81,128,128) fp32. B zero-padded.
//
// R8: R7's deep pipeline with the register-clobber fix: A-role and B-role use
// DISJOINT prefetch register sets (threads 0..63 hold both roles). CC=8 (16
// chunks), 2-register-set rotation: chunk k+3's loads issued at iter k,
// consumed at iter k+2 -> issue-to-use = 2 iterations >= HBM latency.
// f16 pair-packing + v_dot2_f32_f16 + LDS dbuf (1 barrier/chunk).
// Block = 192 thr (3 waves) = (b, y, p-group); LDS 17.9 KB.

typedef __fp16 h2 __attribute__((ext_vector_type(2)));

#define BW2 144   // padded B row in h2 units; j = x+4, valid j in [0,136), pad 144

#if __has_builtin(__builtin_amdgcn_fdot2)
  #define FDOT2(a, b, c) __builtin_amdgcn_fdot2((a), (b), (c), false)
#else
  static __device__ inline float FDOT2(h2 a, h2 b, float c) {
      return c + (float)a.x * (float)b.x + (float)a.y * (float)b.y;
  }
#endif

static __device__ inline float pk2f(float lo, float hi) {
    h2 v = __builtin_amdgcn_cvt_pkrtz(lo, hi);   // (f16(lo), f16(hi)) packed
    return __builtin_bit_cast(float, v);
}
static __device__ inline h2 f2h2(float f) { return __builtin_bit_cast(h2, f); }

__global__ __launch_bounds__(192, 4)
void corr_kernel(const float* __restrict__ A, const float* __restrict__ B,
                 float* __restrict__ out)
{
    const int bidx = blockIdx.x;
    const int bb = bidx & 7;          // batch -> XCD affinity
    const int t2 = bidx >> 3;
    const int y  = t2 & 127;
    const int pg = t2 >> 7;           // p-group 0..2

    const int tid  = threadIdx.x;     // 0..191
    const int wave = tid >> 6;        // 0..2
    const int lane = tid & 63;
    const int cs   = lane >> 5;       // base pair-select (lane handles pairs cs, cs+2)
    const int x0   = (lane & 31) << 2;
    const int pr   = pg * 3 + wave;   // 0..8 -> p = pr-4

    __shared__ h2 a_s[2][4][128];     // [buf][pair][x]          pairs 0..3 = 8 channels
    __shared__ h2 b_s[2][3][4][BW2];  // [buf][row-slot][pair][j]

    // one-time zero of b_s: pads (j<4, j>=132) and OOB rows stay zero forever
    {
        float4* pb = (float4*)&b_s[0][0][0][0];
        const int nb = 2 * 3 * 4 * BW2 / 4;   // 864 float4
        for (int i = tid; i < nb; i += 192) pb[i] = make_float4(0.f, 0.f, 0.f, 0.f);
    }

    float acc[9][4];
    #pragma unroll
    for (int q = 0; q < 9; ++q)
        #pragma unroll
        for (int i = 0; i < 4; ++i) acc[q][i] = 0.f;

    const long plane = 128L * 128L;
    const float* Abase = A + (long)bb * 128 * plane + (long)y * 128;
    const float* Bbase = B + (long)bb * 128 * plane;

    // B staging: 6 units (3 row-slots x 2 quads) x 32 cols; each thread covers
    // pairs {bq, bq+2} of the 8-channel chunk -> 4 f4 loads, 2 packed writes.
    const int i4  = (tid & 31) << 2;     // float column
    const int rp  = tid >> 5;            // 0..5
    const int brw = rp >> 1;             // row slot 0..2
    const int bq  = rp & 1;              // pair base 0/1 -> pairs bq, bq+2
    const int bys = y + pg * 3 + brw - 4;
    const bool bval = (unsigned)bys < 128u;
    const float* Bsrc = Bbase + (long)bys * 128 + i4;   // + c*plane per chunk

    // A staging: threads < 64 (IN ADDITION to their B role): quad aq -> pairs {aq, aq+2}
    const bool aact = tid < 64;
    const int aq = (tid >> 5) & 1;

    // DISJOINT register sets for the two roles (R7 bug: these were shared)
    float4 rsb[2][4], rsa[2][4];
    #pragma unroll
    for (int s = 0; s < 2; ++s)
        #pragma unroll
        for (int i = 0; i < 4; ++i) {
            rsb[s][i] = make_float4(0.f, 0.f, 0.f, 0.f);
            rsa[s][i] = make_float4(0.f, 0.f, 0.f, 0.f);
        }

    auto load_chunk = [&](int ch0, int s) {
        if (bval) {
            // pairs bq, bq+2 -> channels ch0 + {2bq, 2bq+1, 2bq+4, 2bq+5}
            const long c0 = (long)(ch0 + (bq << 1)) * plane;
            rsb[s][0] = *(const float4*)(Bsrc + c0);
            rsb[s][1] = *(const float4*)(Bsrc + c0 + plane);
            rsb[s][2] = *(const float4*)(Bsrc + c0 + 4 * plane);
            rsb[s][3] = *(const float4*)(Bsrc + c0 + 5 * plane);
        }
        if (aact) {
            const long c0 = (long)(ch0 + (aq << 1)) * plane;
            rsa[s][0] = *(const float4*)(Abase + c0 + i4);
            rsa[s][1] = *(const float4*)(Abase + c0 + plane + i4);
            rsa[s][2] = *(const float4*)(Abase + c0 + 4 * plane + i4);
            rsa[s][3] = *(const float4*)(Abase + c0 + 5 * plane + i4);
        }
    };
    auto write_stage = [&](int buf, int s) {
        if (bval) {
            float4 w0, w1;
            w0.x = pk2f(rsb[s][0].x, rsb[s][1].x);
            w0.y = pk2f(rsb[s][0].y, rsb[s][1].y);
            w0.z = pk2f(rsb[s][0].z, rsb[s][1].z);
            w0.w = pk2f(rsb[s][0].w, rsb[s][1].w);
            w1.x = pk2f(rsb[s][2].x, rsb[s][3].x);
            w1.y = pk2f(rsb[s][2].y, rsb[s][3].y);
            w1.z = pk2f(rsb[s][2].z, rsb[s][3].z);
            w1.w = pk2f(rsb[s][2].w, rsb[s][3].w);
            *(float4*)&b_s[buf][brw][bq][4 + i4]     = w0;
            *(float4*)&b_s[buf][brw][bq + 2][4 + i4] = w1;
        }
        if (aact) {
            float4 w0, w1;
            w0.x = pk2f(rsa[s][0].x, rsa[s][1].x);
            w0.y = pk2f(rsa[s][0].y, rsa[s][1].y);
            w0.z = pk2f(rsa[s][0].z, rsa[s][1].z);
            w0.w = pk2f(rsa[s][0].w, rsa[s][1].w);
            w1.x = pk2f(rsa[s][2].x, rsa[s][3].x);
            w1.y = pk2f(rsa[s][2].y, rsa[s][3].y);
            w1.z = pk2f(rsa[s][2].z, rsa[s][3].z);
            w1.w = pk2f(rsa[s][2].w, rsa[s][3].w);
            *(float4*)&a_s[buf][aq][i4]     = w0;
            *(float4*)&a_s[buf][aq + 2][i4] = w1;
        }
    };

    // prologue: chunk0 -> set0, chunk1 -> set1; stage chunk0; chunk2 -> set0
    load_chunk(0, 0);
    load_chunk(8, 1);
    __syncthreads();          // zero-init visible before first stage writes
    write_stage(0, 0);
    load_chunk(16, 0);
    __syncthreads();          // buf0 (chunk0) ready

    // 16 chunks of 8 channels
    for (int k = 0; k < 16; ++k) {
        const int buf = k & 1;
        const int ns  = (k + 1) & 1;
        if (k + 1 < 16) write_stage(ns, ns);            // chunk k+1 (loaded at k-2)
        if (k + 3 < 16) load_chunk((k + 3) << 3, ns);   // issue chunk k+3
        // compute chunk k from buf: pairs cs, cs+2
        #pragma unroll
        for (int pp = 0; pp < 2; ++pp) {
            const int pa = cs + (pp << 1);
            const float4 av = *(const float4*)&a_s[buf][pa][x0];
            const float4 b0 = *(const float4*)&b_s[buf][wave][pa][x0];
            const float4 b1 = *(const float4*)&b_s[buf][wave][pa][x0 + 4];
            const float4 b2 = *(const float4*)&b_s[buf][wave][pa][x0 + 8];
            const h2 a2[4] = { f2h2(av.x), f2h2(av.y), f2h2(av.z), f2h2(av.w) };
            const h2 w[12] = { f2h2(b0.x), f2h2(b0.y), f2h2(b0.z), f2h2(b0.w),
                               f2h2(b1.x), f2h2(b1.y), f2h2(b1.z), f2h2(b1.w),
                               f2h2(b2.x), f2h2(b2.y), f2h2(b2.z), f2h2(b2.w) };
            #pragma unroll
            for (int q = 0; q < 9; ++q)
                #pragma unroll
                for (int i = 0; i < 4; ++i)
                    acc[q][i] = FDOT2(a2[i], w[q + i], acc[q][i]);
        }
        __syncthreads();
    }

    // combine pair-split halves (lane L += lane L+32)
    #pragma unroll
    for (int q = 0; q < 9; ++q)
        #pragma unroll
        for (int i = 0; i < 4; ++i)
            acc[q][i] += __shfl_down(acc[q][i], 32);

    if (cs == 0) {
        const float scale = 1.0f / 128.0f;
        float* obase = out + (((long)bb * 81 + (long)pr * 9) * 128 + y) * 128 + x0;
        #pragma unroll
        for (int q = 0; q < 9; ++q) {
            const float4 v = make_float4(acc[q][0] * scale, acc[q][1] * scale,
                                         acc[q][2] * scale, acc[q][3] * scale);
            *(float4*)(obase + (long)q * plane) = v;
        }
    }
}

extern "C" void kernel_launch(void* const* d_in, const int* in_sizes, int n_in,
                              void* d_out, int out_size, void* d_ws, size_t ws_size,
                              hipStream_t stream) {
    const float* a = (const float*)d_in[0];
    const float* b = (const float*)d_in[1];
    float* out = (float*)d_out;
    // grid: 8 batches * 128 y * 3 p-groups = 3072 blocks; 192 threads (3 waves)
    hipLaunchKernelGGL(corr_kernel, dim3(3072), dim3(192), 0, stream, a, b, out);
}

// Round 9
// 210.846 us; speedup vs baseline: 2.2864x; 2.2864x over previous
//
#include <hip/hip_runtime.h>

// Correlation: out[b,(p+4)*9+(q+4),y,x] = (1/128) * sum_c A[b,c,y,x]*B[b,c,y+p,x+q]
// A,B = (8,128,128,128) fp32; out = (8,81,128,128) fp32. B zero-padded.
//
// R9: R8's 3-ahead register pipeline with the SCRATCH fix: the chunk loop is
// unrolled 2-wide so all set/buf indices are compile-time literals -> prefetch
// arrays stay in VGPRs (R8 spilled ~1.5GB to scratch b/c of runtime indices).
// Staging rebalanced: all threads carry 4 B-f4/set; threads 64..191 add 2 A-f4.
// f16 pair-packing + v_dot2_f32_f16 + LDS dbuf (1 barrier/chunk), CC=8.
// Block = 192 thr (3 waves) = (b, y, p-group); LDS 17.9 KB.

typedef __fp16 h2 __attribute__((ext_vector_type(2)));

#define BW2 144   // padded B row in h2 units; j = x+4, valid j in [0,136), pad 144

#if __has_builtin(__builtin_amdgcn_fdot2)
  #define FDOT2(a, b, c) __builtin_amdgcn_fdot2((a), (b), (c), false)
#else
  static __device__ inline float FDOT2(h2 a, h2 b, float c) {
      return c + (float)a.x * (float)b.x + (float)a.y * (float)b.y;
  }
#endif

static __device__ inline float pk2f(float lo, float hi) {
    h2 v = __builtin_amdgcn_cvt_pkrtz(lo, hi);   // (f16(lo), f16(hi)) packed
    return __builtin_bit_cast(float, v);
}
static __device__ inline h2 f2h2(float f) { return __builtin_bit_cast(h2, f); }

__global__ __launch_bounds__(192, 3)
void corr_kernel(const float* __restrict__ A, const float* __restrict__ B,
                 float* __restrict__ out)
{
    const int bidx = blockIdx.x;
    const int bb = bidx & 7;          // batch -> XCD affinity
    const int t2 = bidx >> 3;
    const int y  = t2 & 127;
    const int pg = t2 >> 7;           // p-group 0..2

    const int tid  = threadIdx.x;     // 0..191
    const int wave = tid >> 6;        // 0..2
    const int lane = tid & 63;
    const int cs   = lane >> 5;       // lane computes pairs cs, cs+2
    const int x0   = (lane & 31) << 2;
    const int pr   = pg * 3 + wave;   // 0..8 -> p = pr-4

    __shared__ h2 a_s[2][4][128];     // [buf][pair][x]   pairs 0..3 = 8 channels
    __shared__ h2 b_s[2][3][4][BW2];  // [buf][row][pair][j]

    // one-time zero of b_s: pads and OOB rows stay zero forever
    {
        float4* pb = (float4*)&b_s[0][0][0][0];
        const int nb = 2 * 3 * 4 * BW2 / 4;   // 864 float4
        for (int i = tid; i < nb; i += 192) pb[i] = make_float4(0.f, 0.f, 0.f, 0.f);
    }

    float acc[9][4];
    #pragma unroll
    for (int q = 0; q < 9; ++q)
        #pragma unroll
        for (int i = 0; i < 4; ++i) acc[q][i] = 0.f;

    const long plane = 128L * 128L;
    const float* Abase = A + (long)bb * 128 * plane + (long)y * 128;
    const float* Bbat  = B + (long)bb * 128 * plane;

    // ---- B staging (ALL threads, 2 units): unit = (row, pair, col) -> 2 f4 loads,
    // 1 packed write. 12 row-pairs x 32 cols = 384 units = 192 thr x 2.
    const int col = tid & 31;
    const int c4  = col << 2;
    const int rp0 = tid >> 5;            // 0..5
    const int rp1 = rp0 + 6;             // 6..11
    const int row0 = rp0 >> 2, pair0 = rp0 & 3;
    const int row1 = rp1 >> 2, pair1 = rp1 & 3;
    const int ys0 = y + pg * 3 + row0 - 4;
    const int ys1 = y + pg * 3 + row1 - 4;
    const bool v0 = (unsigned)ys0 < 128u;
    const bool v1 = (unsigned)ys1 < 128u;
    const float* Bs0 = Bbat + (long)ys0 * 128 + c4;
    const float* Bs1 = Bbat + (long)ys1 * 128 + c4;

    // ---- A staging (threads 64..191, 1 unit): 4 pairs x 32 cols = 128 units
    const bool aact = tid >= 64;
    const int ua    = tid - 64;
    const int pairA = (ua >> 5) & 3;
    const int cA4   = (ua & 31) << 2;

    float4 rsb[2][4], rsa[2][2];
    #pragma unroll
    for (int s = 0; s < 2; ++s) {
        #pragma unroll
        for (int i = 0; i < 4; ++i) rsb[s][i] = make_float4(0.f, 0.f, 0.f, 0.f);
        #pragma unroll
        for (int i = 0; i < 2; ++i) rsa[s][i] = make_float4(0.f, 0.f, 0.f, 0.f);
    }

    auto load_chunk = [&](int ch0, int s) {
        if (v0) {
            const long cb = (long)(ch0 + (pair0 << 1)) * plane;
            rsb[s][0] = *(const float4*)(Bs0 + cb);
            rsb[s][1] = *(const float4*)(Bs0 + cb + plane);
        }
        if (v1) {
            const long cb = (long)(ch0 + (pair1 << 1)) * plane;
            rsb[s][2] = *(const float4*)(Bs1 + cb);
            rsb[s][3] = *(const float4*)(Bs1 + cb + plane);
        }
        if (aact) {
            const long ca = (long)(ch0 + (pairA << 1)) * plane;
            rsa[s][0] = *(const float4*)(Abase + ca + cA4);
            rsa[s][1] = *(const float4*)(Abase + ca + plane + cA4);
        }
    };
    auto write_stage = [&](int buf, int s) {
        if (v0) {
            float4 w;
            w.x = pk2f(rsb[s][0].x, rsb[s][1].x);
            w.y = pk2f(rsb[s][0].y, rsb[s][1].y);
            w.z = pk2f(rsb[s][0].z, rsb[s][1].z);
            w.w = pk2f(rsb[s][0].w, rsb[s][1].w);
            *(float4*)&b_s[buf][row0][pair0][4 + c4] = w;
        }
        if (v1) {
            float4 w;
            w.x = pk2f(rsb[s][2].x, rsb[s][3].x);
            w.y = pk2f(rsb[s][2].y, rsb[s][3].y);
            w.z = pk2f(rsb[s][2].z, rsb[s][3].z);
            w.w = pk2f(rsb[s][2].w, rsb[s][3].w);
            *(float4*)&b_s[buf][row1][pair1][4 + c4] = w;
        }
        if (aact) {
            float4 w;
            w.x = pk2f(rsa[s][0].x, rsa[s][1].x);
            w.y = pk2f(rsa[s][0].y, rsa[s][1].y);
            w.z = pk2f(rsa[s][0].z, rsa[s][1].z);
            w.w = pk2f(rsa[s][0].w, rsa[s][1].w);
            *(float4*)&a_s[buf][pairA][cA4] = w;
        }
    };
    auto compute = [&](int buf) {
        #pragma unroll
        for (int pp = 0; pp < 2; ++pp) {
            const int pa = cs + (pp << 1);
            const float4 av = *(const float4*)&a_s[buf][pa][x0];
            const float4 b0 = *(const float4*)&b_s[buf][wave][pa][x0];
            const float4 b1 = *(const float4*)&b_s[buf][wave][pa][x0 + 4];
            const float4 b2 = *(const float4*)&b_s[buf][wave][pa][x0 + 8];
            const h2 a2[4] = { f2h2(av.x), f2h2(av.y), f2h2(av.z), f2h2(av.w) };
            const h2 w[12] = { f2h2(b0.x), f2h2(b0.y), f2h2(b0.z), f2h2(b0.w),
                               f2h2(b1.x), f2h2(b1.y), f2h2(b1.z), f2h2(b1.w),
                               f2h2(b2.x), f2h2(b2.y), f2h2(b2.z), f2h2(b2.w) };
            #pragma unroll
            for (int q = 0; q < 9; ++q)
                #pragma unroll
                for (int i = 0; i < 4; ++i)
                    acc[q][i] = FDOT2(a2[i], w[q + i], acc[q][i]);
        }
    };

    // prologue: chunk0 -> set0, chunk1 -> set1; stage chunk0; chunk2 -> set0
    load_chunk(0, 0);
    load_chunk(8, 1);
    __syncthreads();          // zero-init visible before first stage writes
    write_stage(0, 0);
    load_chunk(16, 0);
    __syncthreads();          // buf0 (chunk0) ready

    // 16 chunks of 8 channels; 2 chunks per body -> all indices literal
    for (int j = 0; j < 8; ++j) {
        // k = 2j (compute buf0): stage chunk 2j+1 (set1 -> buf1); load 2j+3 -> set1
        write_stage(1, 1);
        if (j <= 6) load_chunk((2 * j + 3) << 3, 1);
        compute(0);
        __syncthreads();
        // k = 2j+1 (compute buf1): stage chunk 2j+2 (set0 -> buf0); load 2j+4 -> set0
        if (j <= 6) write_stage(0, 0);
        if (j <= 5) load_chunk((2 * j + 4) << 3, 0);
        compute(1);
        __syncthreads();
    }

    // combine pair-split halves (lane L += lane L+32)
    #pragma unroll
    for (int q = 0; q < 9; ++q)
        #pragma unroll
        for (int i = 0; i < 4; ++i)
            acc[q][i] += __shfl_down(acc[q][i], 32);

    if (cs == 0) {
        const float scale = 1.0f / 128.0f;
        float* obase = out + (((long)bb * 81 + (long)pr * 9) * 128 + y) * 128 + x0;
        #pragma unroll
        for (int q = 0; q < 9; ++q) {
            const float4 v = make_float4(acc[q][0] * scale, acc[q][1] * scale,
                                         acc[q][2] * scale, acc[q][3] * scale);
            *(float4*)(obase + (long)q * plane) = v;
        }
    }
}

extern "C" void kernel_launch(void* const* d_in, const int* in_sizes, int n_in,
                              void* d_out, int out_size, void* d_ws, size_t ws_size,
                              hipStream_t stream) {
    const float* a = (const float*)d_in[0];
    const float* b = (const float*)d_in[1];
    float* out = (float*)d_out;
    // grid: 8 batches * 128 y * 3 p-groups = 3072 blocks; 192 threads (3 waves)
    hipLaunchKernelGGL(corr_kernel, dim3(3072), dim3(192), 0, stream, a, b, out);
}